// Round 4
// baseline (330.802 us; speedup 1.0000x reference)
//
#include <hip/hip_runtime.h>
#include <math.h>

// ---------------------------------------------------------------------------
// R8 (occupancy: 2 -> 4 waves/SIMD via register diet):
//   R7 rocprof: VGPR=148 (2 waves/SIMD), VALUBusy 9.6%, HBM 9.9%, and a
//   replay pass with FETCH~0.5MB (X L3-resident) ran at the SAME 131 us ->
//   latency-bound, not BW-bound. R4/R5/R7 all ~54 us clean because all sat
//   at 2 waves/SIMD (w[4][4]=64 VGPR was the fixed tax).
//   R8 register diet:
//     - 49-lane W scheme: lane l<49 owns 16 CONTIGUOUS W1 rows (16 VGPR,
//       was 64). Lanes 49-63 carry w=0 and contribute zeros.
//     - iteration = 2 samples (a[8]); ping-pong 4 samples in flight (64 r).
//     - reduction: 8 values over 64 lanes = 7 exchange + 3 fixup shuffles.
//   Core live set ~112 VGPR; __launch_bounds__(256,4) caps at 128 ->
//   4 waves/SIMD. 16 samples/wave, batched 16-lane epilogue, 1024 blocks
//   x 4 waves = 4096 waves = exact one-shot residency at 4 slots/SIMD.
// ---------------------------------------------------------------------------

constexpr int ROW  = 784;   // floats per input row
constexpr int ROW4 = 196;   // float4 per input row

__device__ __forceinline__ void apply_rx(float (&sr)[16], float (&si)[16],
                                         int mask, float c, float s)
{
    #pragma unroll
    for (int i = 0; i < 16; i++) {
        if (!(i & mask)) {
            int j = i | mask;
            float x0 = sr[i], y0 = si[i], x1 = sr[j], y1 = si[j];
            sr[i] = fmaf(c, x0,  s * y1);   // Re(c*s0 - i*s*s1)
            si[i] = fmaf(c, y0, -s * x1);   // Im(c*s0 - i*s*s1)
            sr[j] = fmaf(c, x1,  s * y0);   // Re(-i*s*s0 + c*s1)
            si[j] = fmaf(c, y1, -s * x0);   // Im(-i*s*s0 + c*s1)
        }
    }
}

__device__ __forceinline__ void apply_cnot(float (&sr)[16], float (&si)[16],
                                           int cmask, int tmask)
{
    #pragma unroll
    for (int i = 0; i < 16; i++) {
        if ((i & cmask) && !(i & tmask)) {
            int j = i | tmask;
            float tr = sr[i]; sr[i] = sr[j]; sr[j] = tr;
            float ti = si[i]; si[i] = si[j]; si[j] = ti;
        }
    }
}

// ---- macros keep all array indexing compile-time (no scratch; rule #20) ----
#define FMA_ONE(xv, wrow, o0) \
    a[(o0)+0] = fmaf(xv, wrow.x, a[(o0)+0]); \
    a[(o0)+1] = fmaf(xv, wrow.y, a[(o0)+1]); \
    a[(o0)+2] = fmaf(xv, wrow.z, a[(o0)+2]); \
    a[(o0)+3] = fmaf(xv, wrow.w, a[(o0)+3]);

// Two samples: xb[0..3] -> a[0..3], xb[4..7] -> a[4..7].
#define FMA2(xb) { \
    _Pragma("unroll") \
    for (int i = 0; i < 4; i++) { \
        FMA_ONE(xb[i].x, w[i][0], 0) FMA_ONE(xb[4+i].x, w[i][0], 4) \
        FMA_ONE(xb[i].y, w[i][1], 0) FMA_ONE(xb[4+i].y, w[i][1], 4) \
        FMA_ONE(xb[i].z, w[i][2], 0) FMA_ONE(xb[4+i].z, w[i][2], 4) \
        FMA_ONE(xb[i].w, w[i][3], 0) FMA_ONE(xb[4+i].w, w[i][3], 4) \
    } }

#define CLMP(v) (((v) < sl) ? (v) : sl)

// Lane l covers float4 chunks 4l..4l+3 (64B contiguous) of each row.
#define LOAD2(dst, sA, sB) { \
    const float4* rA_ = X4 + (size_t)CLMP(sA) * ROW4; \
    const float4* rB_ = X4 + (size_t)CLMP(sB) * ROW4; \
    dst[0] = rA_[c0]; dst[1] = rA_[c1]; dst[2] = rA_[c2]; dst[3] = rA_[c3]; \
    dst[4] = rB_[c0]; dst[5] = rB_[c1]; dst[6] = rB_[c2]; dst[7] = rB_[c3]; }

__global__ __launch_bounds__(256, 4) void fused_kernel(
    const float* __restrict__ X,    // [B,784]
    const float* __restrict__ W1,   // [784,4]
    const float* __restrict__ b1,   // [4]
    const float* __restrict__ qw,   // [2,4]
    const float* __restrict__ W2,   // [4,32]
    const float* __restrict__ b2,   // [32]
    const float* __restrict__ W3,   // [32,2]
    const float* __restrict__ b3,   // [2]
    float* __restrict__ out,        // [B,2]
    int B)
{
    const int lane = threadIdx.x & 63;
    const int wid  = (blockIdx.x * 256 + threadIdx.x) >> 6;

    const float4* X4   = reinterpret_cast<const float4*>(X);
    const float4* W1f4 = reinterpret_cast<const float4*>(W1);

    // x-chunk indices for this lane (clamped for lanes >= 49; their w = 0).
    const int c0 = (4 * lane     < ROW4) ? 4 * lane     : ROW4 - 1;
    const int c1 = (4 * lane + 1 < ROW4) ? 4 * lane + 1 : ROW4 - 1;
    const int c2 = (4 * lane + 2 < ROW4) ? 4 * lane + 2 : ROW4 - 1;
    const int c3 = (4 * lane + 3 < ROW4) ? 4 * lane + 3 : ROW4 - 1;

    // W1 rows 16*lane .. 16*lane+15 in 16 VGPRs (contiguous; 49 lanes active).
    const bool wok = (lane < 49);
    const float4 zero4 = make_float4(0.f, 0.f, 0.f, 0.f);
    float4 w[4][4];
    #pragma unroll
    for (int i = 0; i < 4; i++) {
        #pragma unroll
        for (int c = 0; c < 4; c++) {
            float4 t = W1f4[wok ? (16 * lane + 4 * i + c) : 0];
            w[i][c] = wok ? t : zero4;
        }
    }

    // After reduction, lane L holds value idx = L>>3, idx = 4t+k
    // (t = sample-in-iteration 0..1, k = output column 0..3).
    const float bl = b1[(lane >> 3) & 3];

    const bool b5  = (lane & 32) != 0;
    const bool b4  = (lane & 16) != 0;
    const bool b3f = (lane & 8)  != 0;

    const int sl = B - 1;

    // Wave owns 16 consecutive samples: 8 iterations x 2.
    const int S = wid * 16;
    if (S >= B) return;

    // Per-lane parked angles: lane j (j<16) ends with sample S+j's 4 angles.
    float p0 = 0.f, p1 = 0.f, p2 = 0.f, p3 = 0.f;

    // Prologue: iterations 0 and 1 in flight.
    float4 xA[8], xB[8];
    LOAD2(xA, S,     S + 1)
    LOAD2(xB, S + 2, S + 3)

    #pragma unroll
    for (int it = 0; it < 8; it++) {
        float4 (&xb)[8] = (it & 1) ? xB : xA;   // static after full unroll

        float a[8];
        #pragma unroll
        for (int i = 0; i < 8; i++) a[i] = 0.f;

        FMA2(xb)
        if (it < 6) {
            const int Sn = S + (it + 2) * 2;
            if (it & 1) { LOAD2(xB, Sn, Sn + 1) }
            else        { LOAD2(xA, Sn, Sn + 1) }
        }

        // ---- exchange-halving reduction: 8 values over 64 lanes ----------
        float v4[4];
        #pragma unroll
        for (int i = 0; i < 4; i++) {
            float kv = b5 ? a[i + 4] : a[i];
            float sv = b5 ? a[i]     : a[i + 4];
            v4[i] = kv + __shfl_xor(sv, 32);
        }
        float v2[2];
        #pragma unroll
        for (int i = 0; i < 2; i++) {
            float kv = b4 ? v4[i + 2] : v4[i];
            float sv = b4 ? v4[i]     : v4[i + 2];
            v2[i] = kv + __shfl_xor(sv, 16);
        }
        float kv = b3f ? v2[1] : v2[0];
        float sv = b3f ? v2[0] : v2[1];
        float v1 = kv + __shfl_xor(sv, 8);
        v1 += __shfl_xor(v1, 4);
        v1 += __shfl_xor(v1, 2);
        v1 += __shfl_xor(v1, 1);

        const float pre_val = fmaxf(v1 + bl, 0.f);   // bias + relu

        // Value idx=4t+k lives at lanes 8*idx..8*idx+7. Lane j parks sample
        // t=j&1 at iteration it=j>>1 (lanes >=16 never match it<8).
        const float g0 = __shfl(pre_val, ((lane & 1) << 5) + 0);
        const float g1 = __shfl(pre_val, ((lane & 1) << 5) + 8);
        const float g2 = __shfl(pre_val, ((lane & 1) << 5) + 16);
        const float g3 = __shfl(pre_val, ((lane & 1) << 5) + 24);
        if ((lane >> 1) == it) { p0 = g0; p1 = g1; p2 = g2; p3 = g3; }
    }

    // ---- ONE batched epilogue: quantum sim + MLP, 16 active lanes --------
    if (lane < 16 && S + lane < B) {
        const int s = S + lane;

        float sr[16], si[16];
        #pragma unroll
        for (int i = 0; i < 16; i++) { sr[i] = 0.f; si[i] = 0.f; }
        sr[0] = 1.f;

        {   // AngleEmbedding: RX(pre_q) on wire q (wire0 = MSB = mask 8)
            float c, sn;
            __sincosf(p0 * 0.5f, &sn, &c); apply_rx(sr, si, 8, c, sn);
            __sincosf(p1 * 0.5f, &sn, &c); apply_rx(sr, si, 4, c, sn);
            __sincosf(p2 * 0.5f, &sn, &c); apply_rx(sr, si, 2, c, sn);
            __sincosf(p3 * 0.5f, &sn, &c); apply_rx(sr, si, 1, c, sn);
        }

        // BasicEntanglerLayers: RX(qw[l,q]) then CNOT ring.
        #pragma unroll
        for (int l = 0; l < 2; l++) {
            #pragma unroll
            for (int q = 0; q < 4; q++) {
                float c, sn;
                __sincosf(qw[l * 4 + q] * 0.5f, &sn, &c);
                apply_rx(sr, si, 8 >> q, c, sn);
            }
            apply_cnot(sr, si, 8, 4);
            apply_cnot(sr, si, 4, 2);
            apply_cnot(sr, si, 2, 1);
            apply_cnot(sr, si, 1, 8);
        }

        float z0 = 0.f, z1 = 0.f, z2 = 0.f, z3 = 0.f;
        #pragma unroll
        for (int i = 0; i < 16; i++) {
            float p = fmaf(sr[i], sr[i], si[i] * si[i]);
            z0 += (i & 8) ? -p : p;
            z1 += (i & 4) ? -p : p;
            z2 += (i & 2) ? -p : p;
            z3 += (i & 1) ? -p : p;
        }
        z0 = (z0 == z0) ? z0 : 0.f;
        z1 = (z1 == z1) ? z1 : 0.f;
        z2 = (z2 == z2) ? z2 : 0.f;
        z3 = (z3 == z3) ? z3 : 0.f;

        float l0 = b3[0], l1 = b3[1];
        #pragma unroll
        for (int k = 0; k < 32; k++) {
            float v = b2[k];
            v = fmaf(z0, W2[k],      v);
            v = fmaf(z1, W2[32 + k], v);
            v = fmaf(z2, W2[64 + k], v);
            v = fmaf(z3, W2[96 + k], v);
            v = fmaxf(v, 0.f);
            l0 = fmaf(v, W3[2 * k],     l0);
            l1 = fmaf(v, W3[2 * k + 1], l1);
        }

        float m  = fmaxf(l0, l1);
        float e0 = __expf(l0 - m), e1 = __expf(l1 - m);
        float inv = 1.f / (e0 + e1);
        reinterpret_cast<float2*>(out)[s] = make_float2(e0 * inv, e1 * inv);
    }
}

// ---------------------------------------------------------------------------
extern "C" void kernel_launch(void* const* d_in, const int* in_sizes, int n_in,
                              void* d_out, int out_size, void* d_ws, size_t ws_size,
                              hipStream_t stream)
{
    const float* X  = (const float*)d_in[0];  // [B,28,28]
    const float* W1 = (const float*)d_in[1];  // [784,4]
    const float* b1 = (const float*)d_in[2];  // [4]
    const float* qw = (const float*)d_in[3];  // [2,4]
    const float* W2 = (const float*)d_in[4];  // [4,32]
    const float* b2 = (const float*)d_in[5];  // [32]
    const float* W3 = (const float*)d_in[6];  // [32,2]
    const float* b3 = (const float*)d_in[7];  // [2]

    const int B = in_sizes[0] / ROW;

    // 1024 blocks x 4 waves x 16 samples = 65536; at <=128 VGPR this is
    // exactly 4 waves/SIMD chip-wide (2x R7's occupancy).
    const int blocks = (B + 63) / 64;
    fused_kernel<<<blocks, 256, 0, stream>>>(X, W1, b1, qw, W2, b2, W3, b3,
                                             (float*)d_out, B);
}

// Round 5
// 295.647 us; speedup vs baseline: 1.1189x; 1.1189x over previous
//
#include <hip/hip_runtime.h>
#include <math.h>

// ---------------------------------------------------------------------------
// R9 (thread-per-sample, scalar-register W — kill the W-VGPR tax):
//   R8 post-mortem: w[4][4] = 16 float4 = 64 VGPR (not 16 — arithmetic
//   error). Live set ~150 vs the 128 cap -> compiler allocated 64 VGPR and
//   spilled: WRITE_SIZE=49.5MB of scratch (out is 0.5MB), FETCH 155MB,
//   dur 294->331. Window model: R4/R5/R7 (no extra traffic) all = 293-294;
//   R6/R8 (spill traffic) = 309/331 -> dur ~= fixed poison fills (~240us)
//   + kernel tail; extra HBM traffic slows the fills.
//   R9: one thread = one sample. W1 index depends only on the uniform loop
//   counter -> s_load into SGPRs (W1[784][4] = one float4/row, perfect
//   s_load_dwordx16 layout). Per chunk: 1 global_load_dwordx4 + 16
//   v_fmac(v,s,v). NO shuffles/reductions/LDS/lane-masking; epilogue at
//   64/64 lanes. 8-slot load ring = 8KB/wave in flight (>=5x Little's law
//   at the grid-limited 1 wave/SIMD). Each 64B X line consumed by 4
//   consecutive instrs of the same wave -> L1-absorbed, traffic = 196MB.
//   VGPR ~64-80, zero spill pressure.
// ---------------------------------------------------------------------------

constexpr int ROW  = 784;   // floats per input row
constexpr int ROW4 = 196;   // float4 per input row

__device__ __forceinline__ void apply_rx(float (&sr)[16], float (&si)[16],
                                         int mask, float c, float s)
{
    #pragma unroll
    for (int i = 0; i < 16; i++) {
        if (!(i & mask)) {
            int j = i | mask;
            float x0 = sr[i], y0 = si[i], x1 = sr[j], y1 = si[j];
            sr[i] = fmaf(c, x0,  s * y1);   // Re(c*s0 - i*s*s1)
            si[i] = fmaf(c, y0, -s * x1);   // Im(c*s0 - i*s*s1)
            sr[j] = fmaf(c, x1,  s * y0);   // Re(-i*s*s0 + c*s1)
            si[j] = fmaf(c, y1, -s * x0);   // Im(-i*s*s0 + c*s1)
        }
    }
}

__device__ __forceinline__ void apply_cnot(float (&sr)[16], float (&si)[16],
                                           int cmask, int tmask)
{
    #pragma unroll
    for (int i = 0; i < 16; i++) {
        if ((i & cmask) && !(i & tmask)) {
            int j = i | tmask;
            float tr = sr[i]; sr[i] = sr[j]; sr[j] = tr;
            float ti = si[i]; si[i] = si[j]; si[j] = ti;
        }
    }
}

// ---- GEMV step macros: static ring slots (rule #20), uniform W index ------
#define FMAS(x, wA, wB, wC, wD) \
    a0 = fmaf(x.x, wA.x, a0); a1 = fmaf(x.x, wA.y, a1); \
    a2 = fmaf(x.x, wA.z, a2); a3 = fmaf(x.x, wA.w, a3); \
    a0 = fmaf(x.y, wB.x, a0); a1 = fmaf(x.y, wB.y, a1); \
    a2 = fmaf(x.y, wB.z, a2); a3 = fmaf(x.y, wB.w, a3); \
    a0 = fmaf(x.z, wC.x, a0); a1 = fmaf(x.z, wC.y, a1); \
    a2 = fmaf(x.z, wC.z, a2); a3 = fmaf(x.z, wC.w, a3); \
    a0 = fmaf(x.w, wD.x, a0); a1 = fmaf(x.w, wD.y, a1); \
    a2 = fmaf(x.w, wD.z, a2); a3 = fmaf(x.w, wD.w, a3);

// Consume slot, reload it from chunk (k)+8 (keeps 8 loads in flight).
#define STEP_R(slot, k) { \
    const float4 x = xb[slot]; \
    xb[slot] = xr[(k) + 8]; \
    const float4 wA = Wf4[4*(k)+0], wB = Wf4[4*(k)+1], \
                 wC = Wf4[4*(k)+2], wD = Wf4[4*(k)+3]; \
    FMAS(x, wA, wB, wC, wD) }

// Consume slot, no reload (drain).
#define STEP_N(slot, k) { \
    const float4 x = xb[slot]; \
    const float4 wA = Wf4[4*(k)+0], wB = Wf4[4*(k)+1], \
                 wC = Wf4[4*(k)+2], wD = Wf4[4*(k)+3]; \
    FMAS(x, wA, wB, wC, wD) }

__global__ __launch_bounds__(256) void fused_kernel(
    const float* __restrict__ X,    // [B,784]
    const float* __restrict__ W1,   // [784,4]
    const float* __restrict__ b1,   // [4]
    const float* __restrict__ qw,   // [2,4]
    const float* __restrict__ W2,   // [4,32]
    const float* __restrict__ b2,   // [32]
    const float* __restrict__ W3,   // [32,2]
    const float* __restrict__ b3,   // [2]
    float* __restrict__ out,        // [B,2]
    int B)
{
    const int s = blockIdx.x * blockDim.x + threadIdx.x;
    if (s >= B) return;

    const float4* __restrict__ xr  = reinterpret_cast<const float4*>(X)
                                     + (size_t)s * ROW4;
    const float4* __restrict__ Wf4 = reinterpret_cast<const float4*>(W1);

    float a0 = 0.f, a1 = 0.f, a2 = 0.f, a3 = 0.f;

    // 8-slot load ring. Slots are compile-time constants everywhere.
    float4 xb[8];
    #pragma unroll
    for (int i = 0; i < 8; i++) xb[i] = xr[i];

    int k = 0;
    #pragma unroll 1            // keep the loop; body is hand-unrolled x8
    for (int m = 0; m < 23; m++) {
        STEP_R(0, k + 0) STEP_R(1, k + 1) STEP_R(2, k + 2) STEP_R(3, k + 3)
        STEP_R(4, k + 4) STEP_R(5, k + 5) STEP_R(6, k + 6) STEP_R(7, k + 7)
        k += 8;
    }
    // k = 184: consume 184..191 (reload 192..195 into slots 0..3), then drain.
    STEP_R(0, 184) STEP_R(1, 185) STEP_R(2, 186) STEP_R(3, 187)
    STEP_N(4, 188) STEP_N(5, 189) STEP_N(6, 190) STEP_N(7, 191)
    STEP_N(0, 192) STEP_N(1, 193) STEP_N(2, 194) STEP_N(3, 195)

    // bias + relu -> the 4 circuit angles (all 64 lanes, no reduction).
    const float p0 = fmaxf(a0 + b1[0], 0.f);
    const float p1 = fmaxf(a1 + b1[1], 0.f);
    const float p2 = fmaxf(a2 + b1[2], 0.f);
    const float p3 = fmaxf(a3 + b1[3], 0.f);

    // ---- quantum sim + MLP, thread-per-sample (64/64 lanes active) -------
    float sr[16], si[16];
    #pragma unroll
    for (int i = 0; i < 16; i++) { sr[i] = 0.f; si[i] = 0.f; }
    sr[0] = 1.f;

    {   // AngleEmbedding: RX(pre_q) on wire q (wire0 = MSB = mask 8)
        float c, sn;
        __sincosf(p0 * 0.5f, &sn, &c); apply_rx(sr, si, 8, c, sn);
        __sincosf(p1 * 0.5f, &sn, &c); apply_rx(sr, si, 4, c, sn);
        __sincosf(p2 * 0.5f, &sn, &c); apply_rx(sr, si, 2, c, sn);
        __sincosf(p3 * 0.5f, &sn, &c); apply_rx(sr, si, 1, c, sn);
    }

    // BasicEntanglerLayers: RX(qw[l,q]) then CNOT ring (0,1)(1,2)(2,3)(3,0)
    #pragma unroll
    for (int l = 0; l < 2; l++) {
        #pragma unroll
        for (int q = 0; q < 4; q++) {
            float c, sn;
            __sincosf(qw[l * 4 + q] * 0.5f, &sn, &c);
            apply_rx(sr, si, 8 >> q, c, sn);
        }
        apply_cnot(sr, si, 8, 4);
        apply_cnot(sr, si, 4, 2);
        apply_cnot(sr, si, 2, 1);
        apply_cnot(sr, si, 1, 8);
    }

    // <Z_q> expectation values
    float z0 = 0.f, z1 = 0.f, z2 = 0.f, z3 = 0.f;
    #pragma unroll
    for (int i = 0; i < 16; i++) {
        float p = fmaf(sr[i], sr[i], si[i] * si[i]);
        z0 += (i & 8) ? -p : p;
        z1 += (i & 4) ? -p : p;
        z2 += (i & 2) ? -p : p;
        z3 += (i & 1) ? -p : p;
    }
    z0 = (z0 == z0) ? z0 : 0.f;
    z1 = (z1 == z1) ? z1 : 0.f;
    z2 = (z2 == z2) ? z2 : 0.f;
    z3 = (z3 == z3) ? z3 : 0.f;

    // post = relu(z @ W2 + b2); logits = post @ W3 + b3 (all W uniform->SGPR)
    float l0 = b3[0], l1 = b3[1];
    #pragma unroll
    for (int kk = 0; kk < 32; kk++) {
        float v = b2[kk];
        v = fmaf(z0, W2[kk],      v);
        v = fmaf(z1, W2[32 + kk], v);
        v = fmaf(z2, W2[64 + kk], v);
        v = fmaf(z3, W2[96 + kk], v);
        v = fmaxf(v, 0.f);
        l0 = fmaf(v, W3[2 * kk],     l0);
        l1 = fmaf(v, W3[2 * kk + 1], l1);
    }

    float m  = fmaxf(l0, l1);
    float e0 = __expf(l0 - m), e1 = __expf(l1 - m);
    float inv = 1.f / (e0 + e1);
    reinterpret_cast<float2*>(out)[s] = make_float2(e0 * inv, e1 * inv);
}

// ---------------------------------------------------------------------------
extern "C" void kernel_launch(void* const* d_in, const int* in_sizes, int n_in,
                              void* d_out, int out_size, void* d_ws, size_t ws_size,
                              hipStream_t stream)
{
    const float* X  = (const float*)d_in[0];  // [B,28,28]
    const float* W1 = (const float*)d_in[1];  // [784,4]
    const float* b1 = (const float*)d_in[2];  // [4]
    const float* qw = (const float*)d_in[3];  // [2,4]
    const float* W2 = (const float*)d_in[4];  // [4,32]
    const float* b2 = (const float*)d_in[5];  // [32]
    const float* W3 = (const float*)d_in[6];  // [32,2]
    const float* b3 = (const float*)d_in[7];  // [2]

    const int B = in_sizes[0] / ROW;

    // Thread-per-sample: 256 blocks x 256 thr = 65536 threads.
    const int blocks = (B + 255) / 256;
    fused_kernel<<<blocks, 256, 0, stream>>>(X, W1, b1, qw, W2, b2, W3, b3,
                                             (float*)d_out, B);
}